// Round 14
// baseline (1453.983 us; speedup 1.0000x reference)
//
#include <hip/hip_runtime.h>
#include <hip/hip_bf16.h>

#define B_ 64
#define K_ 16
#define N_ 4096
#define C_ 384
#define M_ 4096
#define EPS_ 1e-8f

#define NCHUNK_ 16           // 256-row chunks per b
#define TROWS_  16           // rows per LDS stage in sim (24 KB)
#define NSTAGE_ 8            // stages per block (128 rows)

// async global->LDS, 16B per lane, wave-uniform LDS base (+lane*16 in HW)
#define GLDS(gp, lp) __builtin_amdgcn_global_load_lds( \
    (const __attribute__((address_space(1))) unsigned int*)(gp), \
    (__attribute__((address_space(3))) unsigned int*)(lp), 16, 0, 0)

// ---------------------------------------------------------------------------
// init: copy input prototypes into ws and compute their norms
// ---------------------------------------------------------------------------
__global__ __launch_bounds__(384) void init_proto_kernel(
    const float* __restrict__ pin, float* __restrict__ proto,
    float* __restrict__ pnorm)
{
    const int bk = blockIdx.x;
    const int c  = threadIdx.x;            // 384 threads, c == channel
    float v = pin[(size_t)bk * C_ + c];
    proto[(size_t)bk * C_ + c] = v;
    float sq = v * v;
    #pragma unroll
    for (int m = 1; m <= 32; m <<= 1) sq += __shfl_xor(sq, m, 64);
    __shared__ float red[6];
    const int w = c >> 6, lane = c & 63;
    if (lane == 0) red[w] = sq;
    __syncthreads();
    if (c == 0) {
        float t = red[0] + red[1] + red[2] + red[3] + red[4] + red[5];
        pnorm[bk] = sqrtf(t);
    }
}

// ---------------------------------------------------------------------------
// sim: sim[b,k,n] = dot(proto[b,k],feats_row[n]) / max(pnorm*fnorm, EPS)
// LDS-staged pipeline (global_load_lds, linear dest), block-barrier double
// buffer (best-measured variant, round 12). STRIDED chunk layout: lane cc
// reads 16B-chunks {cc+16i} -> 2-way bank access = free.
// NM: 0 = compute row norm + store to fnorm; 1 = load fnorm; 2 = compute only.
// ---------------------------------------------------------------------------
template <int NM>
__global__ __launch_bounds__(256) void sim_kernel(
    const float* __restrict__ proto,   // [B,K,C]
    const float* __restrict__ pnorm,   // [B,K]
    const float* __restrict__ feats,   // rows [nrows, C], per-b stride bstride
    float* __restrict__ fnorm,         // [B,nrows] (store NM=0 / load NM=1)
    float* __restrict__ simout,        // [B,K,nrows]
    int nrows, long long bstride)
{
    const int b    = blockIdx.y;
    const int tile = blockIdx.x;           // 128 rows per block
    const int tid  = threadIdx.x;
    const int wave = tid >> 6;
    const int lane = tid & 63;
    const int kg   = lane & 3;
    const int cc   = lane >> 2;
    const int p    = cc & 1;
    const int q    = (cc >> 1) & 1;

    __shared__ float lbuf[2][TROWS_ * C_];     // 2 x 24 KB

    // writer-lane k mapping and its prototype norm
    const int k_w = (lane & 3) * 4 + 2 * ((lane >> 3) & 1) + ((lane >> 2) & 1);
    const float pn_w = pnorm[b * K_ + (k_w & 15)];

    // prototype fragments in registers: 4 k's x 6 strided 16B chunks
    float4 pr[4][6];
    const float* pb = proto + (size_t)b * K_ * C_;
    #pragma unroll
    for (int j = 0; j < 4; ++j) {
        const float* prow = pb + (size_t)(kg * 4 + j) * C_;
        #pragma unroll
        for (int i = 0; i < 6; ++i)
            pr[j][i] = *(const float4*)(prow + (cc + 16 * i) * 4);
    }

    const float* fb = feats + (size_t)b * bstride;
    const int nbase0 = tile * (TROWS_ * NSTAGE_);

    // stage st -> buffer s: linear 24 KB copy, 6 calls x 4 KB
    const int loff = wave * 256 + lane * 4;    // float offset of this lane's 16B
    #define STAGE_(s, st) do {                                              \
        const float* g_ = fb + (size_t)(nbase0 + (st) * TROWS_) * C_ + loff;\
        float* l_ = &lbuf[s][wave * 256];                                   \
        _Pragma("unroll")                                                   \
        for (int i_ = 0; i_ < 6; ++i_)                                      \
            GLDS(g_ + i_ * 1024, l_ + i_ * 1024);                           \
    } while (0)

    STAGE_(0, 0);
    __syncthreads();

    for (int st = 0; st < NSTAGE_; ++st) {
        if (st + 1 < NSTAGE_) STAGE_((st + 1) & 1, st + 1);

        const float* lb = &lbuf[st & 1][0];
        #pragma unroll
        for (int r = 0; r < 4; ++r) {
            const int row = wave * 4 + r;
            const int n = nbase0 + st * TROWS_ + row;
            const float* frow = lb + row * C_;
            float4 f[6];
            #pragma unroll
            for (int i = 0; i < 6; ++i)
                f[i] = *(const float4*)(frow + (cc + 16 * i) * 4);

            float s0 = 0.f, s1 = 0.f, s2 = 0.f, s3 = 0.f, nsq = 0.f;
            #pragma unroll
            for (int i = 0; i < 6; ++i) {
                if (NM != 1)
                    nsq += f[i].x * f[i].x + f[i].y * f[i].y
                         + f[i].z * f[i].z + f[i].w * f[i].w;
                s0 += f[i].x * pr[0][i].x + f[i].y * pr[0][i].y
                    + f[i].z * pr[0][i].z + f[i].w * pr[0][i].w;
                s1 += f[i].x * pr[1][i].x + f[i].y * pr[1][i].y
                    + f[i].z * pr[1][i].z + f[i].w * pr[1][i].w;
                s2 += f[i].x * pr[2][i].x + f[i].y * pr[2][i].y
                    + f[i].z * pr[2][i].z + f[i].w * pr[2][i].w;
                s3 += f[i].x * pr[3][i].x + f[i].y * pr[3][i].y
                    + f[i].z * pr[3][i].z + f[i].w * pr[3][i].w;
            }
            // fold A: merge {s0,s1} across cc bit0 (lane bit2)
            float sendA = p ? s0 : s1;
            float recvA = __shfl_xor(sendA, 4, 64);
            float a = (p ? s1 : s0) + recvA;
            // fold B: merge {s2,s3}
            float sendB = p ? s2 : s3;
            float recvB = __shfl_xor(sendB, 4, 64);
            float bb = (p ? s3 : s2) + recvB;
            // fold C: merge {a,b} across cc bit1 (lane bit3)
            float sendC = q ? a : bb;
            float recvC = __shfl_xor(sendC, 8, 64);
            float d = (q ? bb : a) + recvC;
            d += __shfl_xor(d, 16, 64);
            d += __shfl_xor(d, 32, 64);

            float fn;
            if (NM == 1) {
                fn = fnorm[(size_t)b * nrows + n];
            } else {
                #pragma unroll
                for (int m = 4; m <= 32; m <<= 1) nsq += __shfl_xor(nsq, m, 64);
                fn = sqrtf(nsq);
                if (NM == 0 && lane == 0) fnorm[(size_t)b * nrows + n] = fn;
            }
            if (lane < 16) {
                const float denom = fmaxf(pn_w * fn, EPS_);
                simout[((size_t)b * K_ + k_w) * (size_t)nrows + n] = d / denom;
            }
        }
        __syncthreads();
    }
    #undef STAGE_
}

// ---------------------------------------------------------------------------
// stats: per (b,k): density->tau->inv (from prev mask), rowmax, rowsum(exp)
// ---------------------------------------------------------------------------
__global__ __launch_bounds__(256) void stats_kernel(
    const float* __restrict__ sim,     // [B,K,N]
    const int* __restrict__ kmaxp,     // [B,N] previous-iteration assignment
    float* __restrict__ inv, float* __restrict__ rowmax,
    float* __restrict__ rowsum, int iter0)
{
    const int bk = blockIdx.x;
    const int b = bk >> 4, k = bk & 15;
    const int t = threadIdx.x;
    const float* row = sim + (size_t)bk * N_;
    const int*   km  = kmaxp + (size_t)b * N_;

    float4 v[4];
    float mx = -3.0e38f, ms = 0.f;
    int mc = 0;
    #pragma unroll
    for (int i = 0; i < 4; ++i) {
        v[i] = ((const float4*)row)[i * 256 + t];
        mx = fmaxf(mx, fmaxf(fmaxf(v[i].x, v[i].y), fmaxf(v[i].z, v[i].w)));
    }
    if (!iter0) {
        #pragma unroll
        for (int i = 0; i < 4; ++i) {
            const int4 kk = ((const int4*)km)[i * 256 + t];
            if (kk.x == k) { ms += v[i].x; mc++; }
            if (kk.y == k) { ms += v[i].y; mc++; }
            if (kk.z == k) { ms += v[i].z; mc++; }
            if (kk.w == k) { ms += v[i].w; mc++; }
        }
    }
    __shared__ float smx[4], sms[4];
    __shared__ int   smc[4];
    #pragma unroll
    for (int m = 1; m <= 32; m <<= 1) {
        mx = fmaxf(mx, __shfl_xor(mx, m, 64));
        ms += __shfl_xor(ms, m, 64);
        mc += __shfl_xor(mc, m, 64);
    }
    const int w = t >> 6, lane = t & 63;
    if (lane == 0) { smx[w] = mx; sms[w] = ms; smc[w] = mc; }
    __syncthreads();
    mx = fmaxf(fmaxf(smx[0], smx[1]), fmaxf(smx[2], smx[3]));
    ms = sms[0] + sms[1] + sms[2] + sms[3];
    mc = smc[0] + smc[1] + smc[2] + smc[3];

    float invv;
    if (iter0) {
        invv = 100.f;                     // 1/(temp*tau0) = 1/(0.1*0.1)
    } else {
        const float d   = (mc >= 1) ? (1.f - ms / (float)mc) : 1.f;
        const float tau = fmaxf(d, 1e-10f);
        invv = 1.f / (0.1f * tau);
    }
    float es = 0.f;
    #pragma unroll
    for (int i = 0; i < 4; ++i) {
        es += expf((v[i].x - mx) * invv) + expf((v[i].y - mx) * invv)
            + expf((v[i].z - mx) * invv) + expf((v[i].w - mx) * invv);
    }
    #pragma unroll
    for (int m = 1; m <= 32; m <<= 1) es += __shfl_xor(es, m, 64);
    __syncthreads();
    if (lane == 0) sms[w] = es;
    __syncthreads();
    if (t == 0) {
        rowmax[bk] = mx;
        rowsum[bk] = sms[0] + sms[1] + sms[2] + sms[3];
        inv[bk]    = invv;
    }
}

// ---------------------------------------------------------------------------
// argmax over k of softmax weight; full-machine grid (16,64). Emits winner
// index + winning weight to global for the (light) chunk-build kernel.
// ---------------------------------------------------------------------------
__global__ __launch_bounds__(256) void argmax_kernel(
    const float* __restrict__ sim, const float* __restrict__ rowmax,
    const float* __restrict__ rowsum, const float* __restrict__ inv,
    int* __restrict__ kmaxo, float* __restrict__ wselo)
{
    const int b = blockIdx.y;
    const int n = blockIdx.x * 256 + threadIdx.x;
    float best = -1.f;
    int bi = 0;
    #pragma unroll
    for (int k = 0; k < K_; ++k) {
        const float s = sim[((size_t)b * K_ + k) * N_ + n];
        const float w = expf((s - rowmax[b * K_ + k]) * inv[b * K_ + k])
                        / rowsum[b * K_ + k];
        if (w > best) { best = w; bi = k; }   // strict > keeps first (jnp tie rule)
    }
    kmaxo[(size_t)b * N_ + n] = bi;
    wselo[(size_t)b * N_ + n] = best;
}

// ---------------------------------------------------------------------------
// build chunk-local sublists: for each (b, chunk of 256 rows) group the rows
// by winning k (n-ascending, deterministic ballot/popc; one wave per chunk).
// Output: cl_n/cl_w [B][N] chunk-relative row idx + weight, grouped by k;
// ccnt/coff [B][NCHUNK][K] per-sublist count and offset within the chunk.
// ---------------------------------------------------------------------------
__global__ __launch_bounds__(256) void build_chunks_kernel(
    const int* __restrict__ kmax, const float* __restrict__ wsel,
    int* __restrict__ cl_n, float* __restrict__ cl_w,
    int* __restrict__ ccnt, int* __restrict__ coff)
{
    const int b = blockIdx.x;
    const int t = threadIdx.x;
    const int wave = t >> 6, lane = t & 63;
    const unsigned long long lt = (1ull << lane) - 1ull;

    for (int ch = wave; ch < NCHUNK_; ch += 4) {
        const int base = ch * 256;
        const int*   km = kmax + (size_t)b * N_ + base;
        const float* wv = wsel + (size_t)b * N_ + base;

        int c16[16];
        #pragma unroll
        for (int k = 0; k < 16; ++k) c16[k] = 0;
        #pragma unroll
        for (int r = 0; r < 4; ++r) {
            const int kk = km[r * 64 + lane];
            #pragma unroll
            for (int k = 0; k < 16; ++k)
                c16[k] += __popcll(__ballot(kk == k));
        }
        int off16[16]; int acc = 0;
        #pragma unroll
        for (int k = 0; k < 16; ++k) { off16[k] = acc; acc += c16[k]; }
        if (lane == 0) {
            #pragma unroll
            for (int k = 0; k < 16; ++k) {
                ccnt[((size_t)b * NCHUNK_ + ch) * K_ + k] = c16[k];
                coff[((size_t)b * NCHUNK_ + ch) * K_ + k] = off16[k];
            }
        }
        int run16[16];
        #pragma unroll
        for (int k = 0; k < 16; ++k) run16[k] = off16[k];
        #pragma unroll
        for (int r = 0; r < 4; ++r) {
            const int n = r * 64 + lane;           // chunk-relative
            const int kk = km[n];
            const float w = wv[n];
            #pragma unroll
            for (int k = 0; k < 16; ++k) {
                const unsigned long long m = __ballot(kk == k);
                if (kk == k) {
                    const int pos = run16[k] + __popcll(m & lt);
                    cl_n[(size_t)b * N_ + base + pos] = n;
                    cl_w[(size_t)b * N_ + base + pos] = w;
                }
                run16[k] += __popcll(m);
            }
        }
    }
}

// ---------------------------------------------------------------------------
// chunk-sorted prototype update: block = (chunk, b) -> 256 CONSECUTIVE rows
// (384 KB window, L2/DRAM-friendly; perfectly load-balanced grid). k iterated
// STATICALLY (full unroll -> 16 named float4 accumulators, no dynamic reg
// indexing); each sublist walked with 1-deep prefetch, 1 FMA per element.
// rg = t/96 takes sublist entries i = off+rg, +4...; rg-partials folded via
// LDS in fixed order. Writes partial[b][chunk][k][C].
// ---------------------------------------------------------------------------
__global__ __launch_bounds__(384) void partial_update_kernel(
    const int* __restrict__ cl_n, const float* __restrict__ cl_w,
    const int* __restrict__ ccnt, const int* __restrict__ coff,
    const float* __restrict__ feats,
    float* __restrict__ partial)       // [B, NCHUNK, K, C]
{
    const int ch = blockIdx.x, b = blockIdx.y;
    const int t = threadIdx.x;
    const int rg = t / 96, ci = t % 96;

    __shared__ int   sn[256];
    __shared__ float sw[256];
    __shared__ int   scnt[16], soff[16];
    if (t < 256) {
        sn[t] = cl_n[(size_t)b * N_ + ch * 256 + t];
        sw[t] = cl_w[(size_t)b * N_ + ch * 256 + t];
    }
    if (t < 16) {
        scnt[t] = ccnt[((size_t)b * NCHUNK_ + ch) * K_ + t];
        soff[t] = coff[((size_t)b * NCHUNK_ + ch) * K_ + t];
    }
    __syncthreads();

    const float4* fb = (const float4*)feats + ((size_t)b * N_ + ch * 256) * 96;

    float4 acc[16];
    #pragma unroll
    for (int k = 0; k < 16; ++k) acc[k] = make_float4(0.f, 0.f, 0.f, 0.f);

    #pragma unroll
    for (int k = 0; k < 16; ++k) {
        const int off = soff[k], end = off + scnt[k];
        int i = off + rg;
        if (i < end) {
            float  w0 = sw[i];
            float4 f0 = fb[(size_t)sn[i] * 96 + ci];
            for (; i < end; i += 4) {
                const int i1 = (i + 4 < end) ? i + 4 : i;   // clamped prefetch
                const float  w1 = sw[i1];
                const float4 f1 = fb[(size_t)sn[i1] * 96 + ci];
                acc[k].x += w0 * f0.x; acc[k].y += w0 * f0.y;
                acc[k].z += w0 * f0.z; acc[k].w += w0 * f0.w;
                w0 = w1; f0 = f1;
            }
        }
    }

    __shared__ float4 sacc[3][96];
    #pragma unroll
    for (int k = 0; k < 16; ++k) {
        __syncthreads();
        if (rg > 0) sacc[rg - 1][ci] = acc[k];
        __syncthreads();
        if (rg == 0) {
            float4 a = acc[k];
            a.x += sacc[0][ci].x + sacc[1][ci].x + sacc[2][ci].x;
            a.y += sacc[0][ci].y + sacc[1][ci].y + sacc[2][ci].y;
            a.z += sacc[0][ci].z + sacc[1][ci].z + sacc[2][ci].z;
            a.w += sacc[0][ci].w + sacc[1][ci].w + sacc[2][ci].w;
            ((float4*)partial)[(((size_t)b * NCHUNK_ + ch) * K_ + k) * 96 + ci] = a;
        }
    }
}

// ---------------------------------------------------------------------------
// stage 2: reduce chunk partials (fixed ascending order) -> proto + pnorm;
// on the last iteration also writes the final prototypes to the output.
// ---------------------------------------------------------------------------
__global__ __launch_bounds__(384) void reduce_update_kernel(
    const float* __restrict__ partial, float* __restrict__ proto,
    float* __restrict__ pnorm, float* __restrict__ outp)
{
    const int bk = blockIdx.x;
    const int b = bk >> 4, k = bk & 15;
    const int c = threadIdx.x;

    float acc = 0.f;
    #pragma unroll 4
    for (int ch = 0; ch < NCHUNK_; ++ch)
        acc += partial[(((size_t)b * NCHUNK_ + ch) * K_ + k) * C_ + c];
    proto[(size_t)bk * C_ + c] = acc;
    if (outp) outp[(size_t)bk * C_ + c] = acc;

    float sq = acc * acc;
    #pragma unroll
    for (int m = 1; m <= 32; m <<= 1) sq += __shfl_xor(sq, m, 64);
    __shared__ float red[6];
    const int w = c >> 6, lane = c & 63;
    if (lane == 0) red[w] = sq;
    __syncthreads();
    if (c == 0) {
        float t = red[0] + red[1] + red[2] + red[3] + red[4] + red[5];
        pnorm[bk] = sqrtf(t);
    }
}

// ---------------------------------------------------------------------------
extern "C" void kernel_launch(void* const* d_in, const int* in_sizes, int n_in,
                              void* d_out, int out_size, void* d_ws, size_t ws_size,
                              hipStream_t stream) {
    const float* pin   = (const float*)d_in[0];   // [B,K,C]
    const float* feats = (const float*)d_in[1];   // [B,N,C]
    const float* forg  = (const float*)d_in[2];   // [M,C]
    float* out = (float*)d_out;

    // workspace carve (floats; every block is a multiple of 4 elems = 16B)
    float* ws = (float*)d_ws;
    size_t o = 0;
    float* proto   = ws + o; o += (size_t)B_ * K_ * C_;            // 393216
    float* pnorm   = ws + o; o += 1024;
    float* inv     = ws + o; o += 1024;
    float* rowmax  = ws + o; o += 1024;
    float* rowsum  = ws + o; o += 1024;
    float* fnorm   = ws + o; o += (size_t)B_ * N_;                 // 262144
    float* wsel    = ws + o; o += (size_t)B_ * N_;                 // 262144
    float* cl_w    = ws + o; o += (size_t)B_ * N_;                 // 262144
    float* sim     = ws + o; o += (size_t)B_ * K_ * N_;            // 4194304
    float* partial = ws + o; o += (size_t)B_ * NCHUNK_ * K_ * C_;  // 6291456
    int*  kmax = (int*)(ws + o); o += (size_t)B_ * N_;
    int*  cl_n = (int*)(ws + o); o += (size_t)B_ * N_;
    int*  ccnt = (int*)(ws + o); o += (size_t)B_ * NCHUNK_ * K_;
    int*  coff = (int*)(ws + o); o += (size_t)B_ * NCHUNK_ * K_;

    const int ROWS_PER_BLK = TROWS_ * NSTAGE_;    // 128

    init_proto_kernel<<<B_ * K_, 384, 0, stream>>>(pin, proto, pnorm);
    // pass 1: compute + store row norms
    sim_kernel<0><<<dim3(N_ / ROWS_PER_BLK, B_), 256, 0, stream>>>(
        proto, pnorm, feats, fnorm, sim, N_, (long long)N_ * C_);

    for (int it = 0; it < 5; ++it) {
        stats_kernel<<<B_ * K_, 256, 0, stream>>>(
            sim, kmax, inv, rowmax, rowsum, it == 0 ? 1 : 0);
        argmax_kernel<<<dim3(N_ / 256, B_), 256, 0, stream>>>(
            sim, rowmax, rowsum, inv, kmax, wsel);
        build_chunks_kernel<<<B_, 256, 0, stream>>>(
            kmax, wsel, cl_n, cl_w, ccnt, coff);
        partial_update_kernel<<<dim3(NCHUNK_, B_), 384, 0, stream>>>(
            cl_n, cl_w, ccnt, coff, feats, partial);
        reduce_update_kernel<<<B_ * K_, 384, 0, stream>>>(
            partial, proto, pnorm, it == 4 ? out : nullptr);
        if (it < 4) {
            sim_kernel<1><<<dim3(N_ / ROWS_PER_BLK, B_), 256, 0, stream>>>(
                proto, pnorm, feats, fnorm, sim, N_, (long long)N_ * C_);
        }
    }

    // final: sim against feats_org -> d_out sim region (norms computed in-pass)
    sim_kernel<2><<<dim3(M_ / ROWS_PER_BLK, B_), 256, 0, stream>>>(
        proto, pnorm, forg, fnorm, out + (size_t)B_ * K_ * C_, M_, 0LL);
}